// Round 1
// baseline (378.684 us; speedup 1.0000x reference)
//
#include <hip/hip_runtime.h>
#include <stdint.h>

// ---------------------------------------------------------------------------
// GCN block: 3 x [ h = leaky_relu(in @ W);  out = (adj + I) @ h ]
// B=64, N=4096, D=16.  Heavy op per layer: GEMM M=4096 (nodes) x
// Ncols=1024 (b*16+d) x K=4096, done in bf16 MFMA with fp32 accum.
// Identity is folded into adj (adjI = adj + I) so one GEMM = one layer.
// Workspace: adjI bf16 [4096][4096] | hT bf16 [1024][4096] | out fp32 [4096][1024]
// ---------------------------------------------------------------------------

typedef __bf16 bf16x8 __attribute__((ext_vector_type(8)));
typedef float  f32x4  __attribute__((ext_vector_type(4)));
typedef unsigned short ushort8 __attribute__((ext_vector_type(8)));

typedef __attribute__((address_space(1))) void* as1_void_p;
typedef __attribute__((address_space(3))) void* as3_void_p;

// async 16B/lane global->LDS (lds dest must be wave-uniform base; HW adds lane*16)
#define GLOAD_LDS16(G, L)                                                      \
  __builtin_amdgcn_global_load_lds((as1_void_p)(G), (as3_void_p)(L), 16, 0, 0)

__device__ __forceinline__ unsigned short f2bf(float f) {
  unsigned u = __float_as_uint(f);
  u += 0x7fffu + ((u >> 16) & 1u);  // RNE
  return (unsigned short)(u >> 16);
}

// ---------------------------------------------------------------------------
// adjI = bf16(adj + I), 4096x4096.  1 thread = 16 contiguous elements.
// ---------------------------------------------------------------------------
__global__ void make_adjI(const float* __restrict__ adj,
                          unsigned short* __restrict__ adjb) {
  size_t t = (size_t)blockIdx.x * 256 + threadIdx.x;
  size_t base = t * 16;
  int n  = (int)(base >> 12);    // row (4096 per row)
  int m0 = (int)(base & 4095);
  const float4* src = (const float4*)(adj + base);
  float4 q0 = src[0], q1 = src[1], q2 = src[2], q3 = src[3];
  float vals[16] = {q0.x,q0.y,q0.z,q0.w, q1.x,q1.y,q1.z,q1.w,
                    q2.x,q2.y,q2.z,q2.w, q3.x,q3.y,q3.z,q3.w};
  ushort8 o0, o1;
#pragma unroll
  for (int j = 0; j < 8; j++) {
    float f = vals[j];     if (m0 + j == n)     f += 1.0f;
    o0[j] = f2bf(f);
  }
#pragma unroll
  for (int j = 0; j < 8; j++) {
    float f = vals[8 + j]; if (m0 + 8 + j == n) f += 1.0f;
    o1[j] = f2bf(f);
  }
  ushort8* dst = (ushort8*)(adjb + base);
  dst[0] = o0; dst[1] = o1;
}

// ---------------------------------------------------------------------------
// h = leaky_relu(in @ W), written TRANSPOSED as bf16: hb[c][m], c=b*16+e, m=n.
// in_bnd=1: in is x (b,n,d) fp32.  in_bnd=0: in is out_ws [n][c] fp32.
// thread: lane = node offset (coalesced hb writes), tid>>6 = b within block.
// ---------------------------------------------------------------------------
__global__ void linear_pack(const float* __restrict__ in,
                            const float* __restrict__ W,
                            unsigned short* __restrict__ hb, int in_bnd) {
  int tid  = threadIdx.x;
  int lane = tid & 63;
  int bq   = tid >> 6;                       // 0..3
  int n = blockIdx.x * 64 + lane;            // node
  int b = blockIdx.y * 4 + bq;               // batch
  size_t off = in_bnd ? (((size_t)b * 4096 + n) * 16)
                      : ((size_t)n * 1024 + b * 16);
  const float4* src = (const float4*)(in + off);
  float4 q0 = src[0], q1 = src[1], q2 = src[2], q3 = src[3];
  float xr[16] = {q0.x,q0.y,q0.z,q0.w, q1.x,q1.y,q1.z,q1.w,
                  q2.x,q2.y,q2.z,q2.w, q3.x,q3.y,q3.z,q3.w};
#pragma unroll
  for (int e = 0; e < 16; e++) {
    float acc = 0.f;
#pragma unroll
    for (int d = 0; d < 16; d++) acc += xr[d] * W[d * 16 + e];  // uniform -> s_load
    acc = acc > 0.f ? acc : 0.2f * acc;      // leaky_relu
    hb[(size_t)(b * 16 + e) * 4096 + n] = f2bf(acc);
  }
}

// ---------------------------------------------------------------------------
// out[n][c] = sum_m adjI[n][m] * h[m][c].   A: adjI bf16 row-major [4096][4096].
// Bm: hT bf16 [1024][4096] (row c, col m) -> B-fragment rows are contiguous.
// Tile: BM=128, BN=64, BK=32. 4 waves, wave tile 64x32 (4x2 MFMA 16x16 tiles).
// Grid 512 blocks (2/CU). XCD swizzle: each XCD owns 4 m-tiles (4MB adj = L2).
// final_mode=0: write out_ws [n][c].  final_mode=1: write d_out (b,n,d).
// ---------------------------------------------------------------------------
__global__ __launch_bounds__(256, 2)
void gemm_adj(const unsigned short* __restrict__ A,
              const unsigned short* __restrict__ Bm,
              float* __restrict__ out, int final_mode) {
  const int K = 4096;
  __shared__ __bf16 a_s[128 * 32];   // 8 KB, rows of 64B
  __shared__ __bf16 b_s[64 * 32];    // 4 KB

  int tid  = threadIdx.x;
  int wave = tid >> 6, lane = tid & 63;

  int lin = blockIdx.x;              // 0..511
  int xcd = lin & 7, ii = lin >> 3;
  int mt = xcd * 4 + (ii & 3);       // 0..31  m-tile
  int ct = ii >> 2;                  // 0..15  c-tile
  int n0 = mt * 128, c0 = ct * 64;

  // staging: lane covers row lr of its 16-row chunk, 16B piece (lane&3)
  int lr  = lane >> 2;
  int lco = (lane & 3) * 8;          // bf16 elems
  const unsigned short* gA0 = A  + (size_t)(n0 + (wave * 2 + 0) * 16 + lr) * K + lco;
  const unsigned short* gA1 = A  + (size_t)(n0 + (wave * 2 + 1) * 16 + lr) * K + lco;
  const unsigned short* gB  = Bm + (size_t)(c0 +  wave * 16       + lr) * K + lco;
  __bf16* lA0 = a_s + (wave * 2 + 0) * 512;   // 1KB chunks, wave-uniform
  __bf16* lA1 = a_s + (wave * 2 + 1) * 512;
  __bf16* lB  = b_s + wave * 512;

  // MFMA fragment addressing
  int i16 = lane & 15, q = lane >> 4;
  int wm = wave >> 1, wn = wave & 1;           // wave grid 2x2
  const __bf16* aP = a_s + ((wm * 64) + i16) * 32 + q * 8;
  const __bf16* bP = b_s + ((wn * 32) + i16) * 32 + q * 8;

  f32x4 acc[4][2] = {};

  for (int k0 = 0; k0 < K; k0 += 32) {
    __syncthreads();                 // prev compute done before overwrite
    GLOAD_LDS16(gA0 + k0, lA0);
    GLOAD_LDS16(gA1 + k0, lA1);
    GLOAD_LDS16(gB  + k0, lB);
    __syncthreads();                 // drains vmcnt -> staging visible
    bf16x8 bf0 = *(const bf16x8*)(bP);
    bf16x8 bf1 = *(const bf16x8*)(bP + 16 * 32);
#pragma unroll
    for (int t = 0; t < 4; t++) {
      bf16x8 af = *(const bf16x8*)(aP + t * 16 * 32);
      acc[t][0] = __builtin_amdgcn_mfma_f32_16x16x32_bf16(af, bf0, acc[t][0], 0, 0, 0);
      acc[t][1] = __builtin_amdgcn_mfma_f32_16x16x32_bf16(af, bf1, acc[t][1], 0, 0, 0);
    }
  }

  // epilogue: D[row=q*4+i][col=i16] per 16x16 tile
#pragma unroll
  for (int t = 0; t < 4; t++)
#pragma unroll
    for (int u = 0; u < 2; u++)
#pragma unroll
      for (int i = 0; i < 4; i++) {
        int n_g = n0 + wm * 64 + t * 16 + q * 4 + i;
        int c_g = c0 + wn * 32 + u * 16 + i16;
        float v = acc[t][u][i];
        if (final_mode)
          out[((size_t)(c_g >> 4) * 4096 + n_g) * 16 + (c_g & 15)];  // placeholder
        if (final_mode)
          out[((size_t)(c_g >> 4) * 4096 + n_g) * 16 + (c_g & 15)] = v;
        else
          out[(size_t)n_g * 1024 + c_g] = v;
      }
}

// ---------------------------------------------------------------------------
extern "C" void kernel_launch(void* const* d_in, const int* in_sizes, int n_in,
                              void* d_out, int out_size, void* d_ws, size_t ws_size,
                              hipStream_t stream) {
  const float* x   = (const float*)d_in[0];
  const float* adj = (const float*)d_in[1];
  // d_in[2] = Identity (unused; folded analytically)
  const float* W0  = (const float*)d_in[3];
  const float* W1  = (const float*)d_in[4];
  const float* W2  = (const float*)d_in[5];
  float* out = (float*)d_out;

  char* ws = (char*)d_ws;
  unsigned short* adjb = (unsigned short*)ws;                       // 33,554,432 B
  unsigned short* hb   = (unsigned short*)(ws + 33554432);          //  8,388,608 B
  float*          ows  = (float*)(ws + 33554432 + 8388608);         // 16,777,216 B

  make_adjI<<<4096, 256, 0, stream>>>(adj, adjb);

  // layer 0
  linear_pack<<<dim3(64, 16), 256, 0, stream>>>(x, W0, hb, 1);
  gemm_adj<<<512, 256, 0, stream>>>(adjb, hb, ows, 0);
  // layer 1
  linear_pack<<<dim3(64, 16), 256, 0, stream>>>(ows, W1, hb, 0);
  gemm_adj<<<512, 256, 0, stream>>>(adjb, hb, ows, 0);
  // layer 2
  linear_pack<<<dim3(64, 16), 256, 0, stream>>>(ows, W2, hb, 0);
  gemm_adj<<<512, 256, 0, stream>>>(adjb, hb, out, 1);
}